// Round 4
// baseline (385.568 us; speedup 1.0000x reference)
//
#include <hip/hip_runtime.h>
#include <hip/hip_bf16.h>
#include <stdint.h>

#define NTOK 8192
#define DIM  512
#define QKVW 1536

typedef __attribute__((ext_vector_type(8))) short bf16x8;
typedef __attribute__((ext_vector_type(4))) float f32x4;

static __device__ __forceinline__ unsigned short f2b(float f) {
    union { float f; unsigned int u; } v; v.f = f;
    unsigned int r = v.u + 0x7fffu + ((v.u >> 16) & 1u);
    return (unsigned short)(r >> 16);
}

static __device__ __forceinline__ void gld_lds16(const void* g, void* l) {
    __builtin_amdgcn_global_load_lds(
        (__attribute__((address_space(1))) void*)(uintptr_t)g,
        (__attribute__((address_space(3))) void*)(uintptr_t)l,
        16, 0, 0);
}

// ---------------- converts ----------------

__global__ void f2b_kernel(const float* __restrict__ src, unsigned short* __restrict__ dst, int n4) {
    int i = blockIdx.x * blockDim.x + threadIdx.x;
    if (i < n4) {
        float4 f = ((const float4*)src)[i];
        ushort4 o;
        o.x = f2b(f.x); o.y = f2b(f.y); o.z = f2b(f.z); o.w = f2b(f.w);
        ((ushort4*)dst)[i] = o;
    }
}

__global__ void bias_concat(const float* __restrict__ bq, const float* __restrict__ bk,
                            const float* __restrict__ bv, float* __restrict__ bc) {
    int i = blockIdx.x * blockDim.x + threadIdx.x;
    if (i < 512)       bc[i] = bq[i];
    else if (i < 1024) bc[i] = bk[i - 512];
    else if (i < 1536) bc[i] = bv[i - 1024];
}

// ---------------- V transpose ----------------
__global__ void transpose_v(const unsigned short* __restrict__ qkv, unsigned short* __restrict__ vt) {
    __shared__ unsigned short t[64][65];
    int j0 = blockIdx.x * 64;
    int d0 = blockIdx.y * 64;
    int tid = threadIdx.x;
    int c  = tid & 63;
    int r4 = tid >> 6;
    #pragma unroll
    for (int r = r4; r < 64; r += 4)
        t[r][c] = qkv[(size_t)(j0 + r) * QKVW + 1024 + d0 + c];
    __syncthreads();
    #pragma unroll
    for (int r = r4; r < 64; r += 4)
        vt[(size_t)(d0 + r) * NTOK + j0 + c] = t[c][r];
}

// ---------------- 128x128 GEMM, C = A * B^T ----------------
// m97 structure: 4 waves (2x2), wave-tile 64x64, acc[4][4], BK=32,
// single LDS buffer + 2 barriers, direct global->LDS staging.
// LDS layout blocked [kq 0..3][row 0..127][16B] -> conflict-free frag reads.
// Epilogue: per-wave LDS transpose pass -> full-128B-line dwordx4 stores
// (kills L2 write-allocate FETCH, the round-3 pathology).
// EPI 0: bf16 store + bias[col]            (QKV projection)
// EPI 1: bf16 store + atomic row sum-sq    (S = Q K^T)
// EPI 2: fp32 partial store (split-K by z) (O = S V)
template <int EPI>
__global__ __launch_bounds__(256, 3) void gemm128(
    const unsigned short* __restrict__ A, int lda,
    const unsigned short* __restrict__ B, int ldb,
    int Ksplit,
    void* __restrict__ Cout, int ldc,
    const float* __restrict__ bias,
    float* __restrict__ rowss) {

    __shared__ __align__(16) char lsAB[16384];      // A 8KB | B 8KB
    __shared__ __align__(16) char epi[4][4352];     // per-wave epilogue scratch

    const int t = threadIdx.x;
    const int l = t & 63, w = t >> 6;
    const int wr = w >> 1, wc = w & 1;

    // bijective XCD swizzle (grid x*y divisible by 8 for all launches)
    const int gx = gridDim.x;
    const int bid = blockIdx.y * gx + blockIdx.x;
    const int cpx = (gridDim.y * gx) >> 3;
    const int swz = (bid & 7) * cpx + (bid >> 3);
    const int bn = swz % gx, bm = swz / gx;

    const int kt0 = blockIdx.z * Ksplit;

    // staging: chunk i = q*256 + w*64 + l  ->  row = i&127, kq = i>>7
    const int rowL = (w & 1) * 64 + l;
    const int kqL  = w >> 1;
    const unsigned short* gA = A + (size_t)(bm * 128 + rowL) * lda + kt0 + kqL * 8;
    const unsigned short* gB = B + (size_t)(bn * 128 + rowL) * ldb + kt0 + kqL * 8;
    char* const dA0 = lsAB + w * 1024;
    char* const dA1 = lsAB + 4096 + w * 1024;
    char* const dB0 = lsAB + 8192 + w * 1024;
    char* const dB1 = lsAB + 12288 + w * 1024;

    f32x4 acc[4][4] = {};

    const int frA = (l >> 4) * 2048 + (wr * 64 + (l & 15)) * 16;
    const int frB = 8192 + (l >> 4) * 2048 + (wc * 64 + (l & 15)) * 16;

    for (int kt = 0; kt < Ksplit; kt += 32) {
        gld_lds16(gA + kt,      dA0);
        gld_lds16(gA + kt + 16, dA1);
        gld_lds16(gB + kt,      dB0);
        gld_lds16(gB + kt + 16, dB1);
        __syncthreads();

        bf16x8 af[4], bf[4];
        #pragma unroll
        for (int m = 0; m < 4; ++m) af[m] = *(const bf16x8*)(lsAB + frA + m * 256);
        #pragma unroll
        for (int n = 0; n < 4; ++n) bf[n] = *(const bf16x8*)(lsAB + frB + n * 256);

        #pragma unroll
        for (int m = 0; m < 4; ++m)
            #pragma unroll
            for (int n = 0; n < 4; ++n)
                acc[m][n] = __builtin_amdgcn_mfma_f32_16x16x32_bf16(af[m], bf[n], acc[m][n], 0, 0, 0);
        __syncthreads();
    }

    const int rbase = bm * 128 + wr * 64;
    const int cbase = bn * 128 + wc * 64;
    const int g4 = (l >> 4) * 4;
    const int lc = l & 15;

    if constexpr (EPI == 0 || EPI == 1) {
        unsigned short* C = (unsigned short*)Cout;
        unsigned short* ep = (unsigned short*)epi[w];   // stride 72 ushorts (144B)
        #pragma unroll
        for (int m = 0; m < 4; ++m) {
            #pragma unroll
            for (int n = 0; n < 4; ++n)
                #pragma unroll
                for (int j = 0; j < 4; ++j) {
                    float v = acc[m][n][j];
                    if constexpr (EPI == 0) v += bias[cbase + n * 16 + lc];
                    ep[(g4 + j) * 72 + n * 16 + lc] = f2b(v);
                }
            #pragma unroll
            for (int t2 = 0; t2 < 2; ++t2) {
                int rloc = t2 * 8 + (l >> 3);
                uint4 v = *(const uint4*)((const char*)epi[w] + rloc * 144 + (l & 7) * 16);
                *(uint4*)&C[(size_t)(rbase + m * 16 + rloc) * ldc + cbase + (l & 7) * 8] = v;
            }
        }
        if constexpr (EPI == 1) {
            #pragma unroll
            for (int m = 0; m < 4; ++m)
                #pragma unroll
                for (int j = 0; j < 4; ++j) {
                    float p = 0.f;
                    #pragma unroll
                    for (int n = 0; n < 4; ++n) {
                        float v = acc[m][n][j];
                        p += v * v;
                    }
                    p += __shfl_xor(p, 1);
                    p += __shfl_xor(p, 2);
                    p += __shfl_xor(p, 4);
                    p += __shfl_xor(p, 8);
                    if ((l & 15) == 0)
                        atomicAdd(&rowss[rbase + m * 16 + g4 + j], p);
                }
        }
    } else {
        float* C = (float*)Cout + (size_t)blockIdx.z * NTOK * ldc;
        float* ep = (float*)epi[w];                     // stride 68 floats (272B)
        #pragma unroll
        for (int m = 0; m < 4; ++m) {
            #pragma unroll
            for (int n = 0; n < 4; ++n)
                #pragma unroll
                for (int j = 0; j < 4; ++j)
                    ep[(g4 + j) * 68 + n * 16 + lc] = acc[m][n][j];
            #pragma unroll
            for (int t2 = 0; t2 < 4; ++t2) {
                int rloc = t2 * 4 + (l >> 4);
                float4 v = *(const float4*)((const char*)epi[w] + rloc * 272 + lc * 16);
                *(float4*)&C[(size_t)(rbase + m * 16 + rloc) * ldc + cbase + lc * 4] = v;
            }
        }
    }
}

// ---------------- split-K reduce + row-norm scale ----------------
__global__ void reduce_scale(const float* __restrict__ p, const float* __restrict__ rss,
                             float* __restrict__ out) {
    int i = blockIdx.x * blockDim.x + threadIdx.x;  // over NTOK*DIM/4
    const size_t stride = (size_t)NTOK * DIM / 4;
    const float4 a = ((const float4*)p)[i];
    const float4 b = ((const float4*)p)[i + stride];
    int r = i >> 7;  // (i*4)/DIM
    float s = 1.0f / fmaxf(sqrtf(rss[r]), 1e-12f);
    float4 o;
    o.x = (a.x + b.x) * s;
    o.y = (a.y + b.y) * s;
    o.z = (a.z + b.z) * s;
    o.w = (a.w + b.w) * s;
    ((float4*)out)[i] = o;
}

extern "C" void kernel_launch(void* const* d_in, const int* in_sizes, int n_in,
                              void* d_out, int out_size, void* d_ws, size_t ws_size,
                              hipStream_t stream) {
    const float* x  = (const float*)d_in[0];
    const float* Wq = (const float*)d_in[1];
    const float* bq = (const float*)d_in[2];
    const float* Wk = (const float*)d_in[3];
    const float* bk = (const float*)d_in[4];
    const float* Wv = (const float*)d_in[5];
    const float* bv = (const float*)d_in[6];
    float* out = (float*)d_out;

    char* ws = (char*)d_ws;
    size_t off = 0;
    auto alloc = [&](size_t bytes) -> void* {
        void* p = ws + off;
        off = (off + bytes + 255) & ~(size_t)255;
        return p;
    };

    unsigned short* xb   = (unsigned short*)alloc((size_t)NTOK * DIM * 2);
    unsigned short* Wb   = (unsigned short*)alloc((size_t)QKVW * DIM * 2);
    float*          bc   = (float*)alloc(QKVW * 4);
    unsigned short* QKV  = (unsigned short*)alloc((size_t)NTOK * QKVW * 2);
    unsigned short* Vt   = (unsigned short*)alloc((size_t)DIM * NTOK * 2);
    float*          rss  = (float*)alloc(NTOK * 4);
    float*          part = (float*)alloc((size_t)2 * NTOK * DIM * 4);
    unsigned short* S    = (unsigned short*)alloc((size_t)NTOK * NTOK * 2);

    // converts
    f2b_kernel<<<(NTOK * DIM / 4 + 255) / 256, 256, 0, stream>>>(x, xb, NTOK * DIM / 4);
    f2b_kernel<<<(DIM * DIM / 4 + 255) / 256, 256, 0, stream>>>(Wq, Wb, DIM * DIM / 4);
    f2b_kernel<<<(DIM * DIM / 4 + 255) / 256, 256, 0, stream>>>(Wk, Wb + DIM * DIM, DIM * DIM / 4);
    f2b_kernel<<<(DIM * DIM / 4 + 255) / 256, 256, 0, stream>>>(Wv, Wb + 2 * DIM * DIM, DIM * DIM / 4);
    bias_concat<<<6, 256, 0, stream>>>(bq, bk, bv, bc);
    hipMemsetAsync(rss, 0, NTOK * 4, stream);

    // QKV = x @ Wb^T + bias   [8192 x 1536], K=512
    gemm128<0><<<dim3(QKVW / 128, NTOK / 128), 256, 0, stream>>>(
        xb, DIM, Wb, DIM, DIM, QKV, QKVW, bc, nullptr);

    // Vt[d][j] from QKV's V block
    transpose_v<<<dim3(NTOK / 64, DIM / 64), 256, 0, stream>>>(QKV, Vt);

    // S = Q @ K^T  [8192 x 8192], K=512 ; rowss += per-row sumsq
    gemm128<1><<<dim3(NTOK / 128, NTOK / 128), 256, 0, stream>>>(
        QKV, QKVW, QKV + DIM, QKVW, DIM, S, NTOK, nullptr, rss);

    // O partials = S @ Vt^T, split-K=2  [8192 x 512]
    gemm128<2><<<dim3(DIM / 128, NTOK / 128, 2), 256, 0, stream>>>(
        S, NTOK, Vt, NTOK, NTOK / 2, part, DIM, nullptr, nullptr);

    // out = (p0+p1) * rsqrt(rowss)
    reduce_scale<<<NTOK * DIM / 4 / 256, 256, 0, stream>>>(part, rss, out);
}

// Round 5
// 370.317 us; speedup vs baseline: 1.0412x; 1.0412x over previous
//
#include <hip/hip_runtime.h>
#include <hip/hip_bf16.h>
#include <stdint.h>

#define NTOK 8192
#define DIM  512
#define QKVW 1536

typedef __attribute__((ext_vector_type(8))) short bf16x8;
typedef __attribute__((ext_vector_type(4))) float f32x4;

static __device__ __forceinline__ unsigned short f2b(float f) {
    union { float f; unsigned int u; } v; v.f = f;
    unsigned int r = v.u + 0x7fffu + ((v.u >> 16) & 1u);
    return (unsigned short)(r >> 16);
}

static __device__ __forceinline__ void gld_lds16(const void* g, void* l) {
    __builtin_amdgcn_global_load_lds(
        (__attribute__((address_space(1))) void*)(uintptr_t)g,
        (__attribute__((address_space(3))) void*)(uintptr_t)l,
        16, 0, 0);
}

#define SBAR() do { __builtin_amdgcn_sched_barrier(0); __builtin_amdgcn_s_barrier(); __builtin_amdgcn_sched_barrier(0); } while (0)
#define VMW0() do { __builtin_amdgcn_sched_barrier(0); asm volatile("s_waitcnt vmcnt(0)" ::: "memory"); __builtin_amdgcn_sched_barrier(0); } while (0)

// ---------------- converts ----------------

__global__ void f2b_kernel(const float* __restrict__ src, unsigned short* __restrict__ dst, int n4) {
    int i = blockIdx.x * blockDim.x + threadIdx.x;
    if (i < n4) {
        float4 f = ((const float4*)src)[i];
        ushort4 o;
        o.x = f2b(f.x); o.y = f2b(f.y); o.z = f2b(f.z); o.w = f2b(f.w);
        ((ushort4*)dst)[i] = o;
    }
}

__global__ void bias_concat(const float* __restrict__ bq, const float* __restrict__ bk,
                            const float* __restrict__ bv, float* __restrict__ bc) {
    int i = blockIdx.x * blockDim.x + threadIdx.x;
    if (i < 512)       bc[i] = bq[i];
    else if (i < 1024) bc[i] = bk[i - 512];
    else if (i < 1536) bc[i] = bv[i - 1024];
}

// ---------------- V transpose ----------------
__global__ void transpose_v(const unsigned short* __restrict__ qkv, unsigned short* __restrict__ vt) {
    __shared__ unsigned short t[64][65];
    int j0 = blockIdx.x * 64;
    int d0 = blockIdx.y * 64;
    int tid = threadIdx.x;
    int c  = tid & 63;
    int r4 = tid >> 6;
    #pragma unroll
    for (int r = r4; r < 64; r += 4)
        t[r][c] = qkv[(size_t)(j0 + r) * QKVW + 1024 + d0 + c];
    __syncthreads();
    #pragma unroll
    for (int r = r4; r < 64; r += 4)
        vt[(size_t)(d0 + r) * NTOK + j0 + c] = t[c][r];
}

// ---------------- 2-phase double-buffered 128x128 GEMM, C = A * B^T ----------------
// T3-minimal recipe: STAGE(t+1) issued BEFORE frag-reads/MFMA of tile t;
// exactly one vmcnt(0) + raw s_barrier per K-tile (no __syncthreads drain).
// 4 waves (2x2), wave-tile 64x64, acc[4][4], BK=32.
// LDS 32KB = 2 x (A 8KB | B 8KB), blocked [kgrp 0..3][row 0..127][16B] ->
// conflict-free ds_read_b128 frags, linear gld_lds dest (rule #21).
// XCD-chunked swizzle: xcd=bid&7 owns 8 bm-rows, sweeps bn in chunks of CH
// so the L2 window (8 A-panels + CH B-panels) stays <= 4MB.
// EPI 0: bf16 store + bias[col]            (QKV projection)
// EPI 1: bf16 store + atomic row sum-sq    (S = Q K^T)
// EPI 2: fp32 partial store (split-K by z) (O = S V)
template <int EPI, int CH>
__global__ __launch_bounds__(256, 4) void gemm2p(
    const unsigned short* __restrict__ A, int lda,
    const unsigned short* __restrict__ B, int ldb,
    int Ksplit,
    void* __restrict__ Cout, int ldc,
    const float* __restrict__ bias,
    float* __restrict__ rowss) {

    __shared__ __align__(16) char lds[32768];

    const int t = threadIdx.x;
    const int l = t & 63, w = t >> 6;
    const int wr = w >> 1, wc = w & 1;

    // XCD-chunked swizzle (gridDim.y % 8 == 0, gridDim.x % CH == 0)
    const int gx = gridDim.x;
    const int nbm = gridDim.y >> 3;
    const int bid = blockIdx.y * gx + blockIdx.x;
    const int xcd = bid & 7, q = bid >> 3;
    const int win = nbm * CH;
    const int grp = q / win, r = q % win;
    const int bm = xcd * nbm + r / CH;
    const int bn = grp * CH + r % CH;

    const int kt0 = blockIdx.z * Ksplit;
    const int NT = Ksplit >> 5;

    // staging: thread (w,l): rows rh=w&1 -> rh*64+l, k-quarter kq=w>>1
    const int rowL = (w & 1) * 64 + l;
    const int kqL  = w >> 1;
    const unsigned short* gA = A + (size_t)(bm * 128 + rowL) * lda + kt0 + kqL * 8;
    const unsigned short* gB = B + (size_t)(bn * 128 + rowL) * ldb + kt0 + kqL * 8;

    f32x4 acc[4][4] = {};

    const int frA0 = (l >> 4) * 2048 + (wr * 64 + (l & 15)) * 16;
    const int frB0 = 8192 + (l >> 4) * 2048 + (wc * 64 + (l & 15)) * 16;

    auto STAGE = [&](int buf, int tt) {
        char* d = lds + buf * 16384 + w * 1024;
        const unsigned short* ga = gA + tt * 32;
        const unsigned short* gb = gB + tt * 32;
        gld_lds16(ga,      d);
        gld_lds16(ga + 16, d + 4096);
        gld_lds16(gb,      d + 8192);
        gld_lds16(gb + 16, d + 12288);
    };

    // prologue: fill buffer 0
    STAGE(0, 0);
    VMW0();
    SBAR();

    int cur = 0;
    for (int tt = 0; tt < NT; ++tt) {
        const bool more = (tt + 1 < NT);
        if (more) STAGE(cur ^ 1, tt + 1);      // issue next-tile loads FIRST
        __builtin_amdgcn_sched_barrier(0);

        const char* lb = lds + cur * 16384;
        bf16x8 af[4], bf[4];
        #pragma unroll
        for (int m = 0; m < 4; ++m) af[m] = *(const bf16x8*)(lb + frA0 + m * 256);
        #pragma unroll
        for (int n = 0; n < 4; ++n) bf[n] = *(const bf16x8*)(lb + frB0 + n * 256);

        #pragma unroll
        for (int m = 0; m < 4; ++m)
            #pragma unroll
            for (int n = 0; n < 4; ++n)
                acc[m][n] = __builtin_amdgcn_mfma_f32_16x16x32_bf16(af[m], bf[n], acc[m][n], 0, 0, 0);

        if (more) {
            VMW0();        // next buffer landed
            SBAR();        // all waves done reading cur
            cur ^= 1;
        }
    }

    const int rbase = bm * 128 + wr * 64;
    const int cbase = bn * 128 + wc * 64;
    const int g4 = (l >> 4) * 4;
    const int lc = l & 15;

    if constexpr (EPI == 0) {
        unsigned short* C = (unsigned short*)Cout;
        #pragma unroll
        for (int m = 0; m < 4; ++m)
            #pragma unroll
            for (int n = 0; n < 4; ++n)
                #pragma unroll
                for (int j = 0; j < 4; ++j) {
                    int rr = rbase + m * 16 + g4 + j;
                    int cc = cbase + n * 16 + lc;
                    C[(size_t)rr * ldc + cc] = f2b(acc[m][n][j] + bias[cc]);
                }
    } else if constexpr (EPI == 1) {
        unsigned short* C = (unsigned short*)Cout;
        #pragma unroll
        for (int m = 0; m < 4; ++m)
            #pragma unroll
            for (int n = 0; n < 4; ++n)
                #pragma unroll
                for (int j = 0; j < 4; ++j) {
                    int rr = rbase + m * 16 + g4 + j;
                    int cc = cbase + n * 16 + lc;
                    C[(size_t)rr * ldc + cc] = f2b(acc[m][n][j]);
                }
        #pragma unroll
        for (int m = 0; m < 4; ++m)
            #pragma unroll
            for (int j = 0; j < 4; ++j) {
                float p = 0.f;
                #pragma unroll
                for (int n = 0; n < 4; ++n) {
                    float v = acc[m][n][j];
                    p += v * v;
                }
                p += __shfl_xor(p, 1);
                p += __shfl_xor(p, 2);
                p += __shfl_xor(p, 4);
                p += __shfl_xor(p, 8);
                if ((l & 15) == 0)
                    atomicAdd(&rowss[rbase + m * 16 + g4 + j], p);
            }
    } else {
        float* C = (float*)Cout + (size_t)blockIdx.z * NTOK * ldc;
        #pragma unroll
        for (int m = 0; m < 4; ++m)
            #pragma unroll
            for (int n = 0; n < 4; ++n)
                #pragma unroll
                for (int j = 0; j < 4; ++j) {
                    int rr = rbase + m * 16 + g4 + j;
                    int cc = cbase + n * 16 + lc;
                    C[(size_t)rr * ldc + cc] = acc[m][n][j];
                }
    }
}

// ---------------- split-K reduce + row-norm scale ----------------
__global__ void reduce_scale(const float* __restrict__ p, const float* __restrict__ rss,
                             float* __restrict__ out) {
    int i = blockIdx.x * blockDim.x + threadIdx.x;  // over NTOK*DIM/4
    const size_t stride = (size_t)NTOK * DIM / 4;
    const float4 a = ((const float4*)p)[i];
    const float4 b = ((const float4*)p)[i + stride];
    int r = i >> 7;  // (i*4)/DIM
    float s = 1.0f / fmaxf(sqrtf(rss[r]), 1e-12f);
    float4 o;
    o.x = (a.x + b.x) * s;
    o.y = (a.y + b.y) * s;
    o.z = (a.z + b.z) * s;
    o.w = (a.w + b.w) * s;
    ((float4*)out)[i] = o;
}

extern "C" void kernel_launch(void* const* d_in, const int* in_sizes, int n_in,
                              void* d_out, int out_size, void* d_ws, size_t ws_size,
                              hipStream_t stream) {
    const float* x  = (const float*)d_in[0];
    const float* Wq = (const float*)d_in[1];
    const float* bq = (const float*)d_in[2];
    const float* Wk = (const float*)d_in[3];
    const float* bk = (const float*)d_in[4];
    const float* Wv = (const float*)d_in[5];
    const float* bv = (const float*)d_in[6];
    float* out = (float*)d_out;

    char* ws = (char*)d_ws;
    size_t off = 0;
    auto alloc = [&](size_t bytes) -> void* {
        void* p = ws + off;
        off = (off + bytes + 255) & ~(size_t)255;
        return p;
    };

    unsigned short* xb   = (unsigned short*)alloc((size_t)NTOK * DIM * 2);
    unsigned short* Wb   = (unsigned short*)alloc((size_t)QKVW * DIM * 2);
    float*          bc   = (float*)alloc(QKVW * 4);
    unsigned short* QKV  = (unsigned short*)alloc((size_t)NTOK * QKVW * 2);
    unsigned short* Vt   = (unsigned short*)alloc((size_t)DIM * NTOK * 2);
    float*          rss  = (float*)alloc(NTOK * 4);
    float*          part = (float*)alloc((size_t)2 * NTOK * DIM * 4);
    unsigned short* S    = (unsigned short*)alloc((size_t)NTOK * NTOK * 2);

    // converts
    f2b_kernel<<<(NTOK * DIM / 4 + 255) / 256, 256, 0, stream>>>(x, xb, NTOK * DIM / 4);
    f2b_kernel<<<(DIM * DIM / 4 + 255) / 256, 256, 0, stream>>>(Wq, Wb, DIM * DIM / 4);
    f2b_kernel<<<(DIM * DIM / 4 + 255) / 256, 256, 0, stream>>>(Wk, Wb + DIM * DIM, DIM * DIM / 4);
    f2b_kernel<<<(DIM * DIM / 4 + 255) / 256, 256, 0, stream>>>(Wv, Wb + 2 * DIM * DIM, DIM * DIM / 4);
    bias_concat<<<6, 256, 0, stream>>>(bq, bk, bv, bc);
    hipMemsetAsync(rss, 0, NTOK * 4, stream);

    // QKV = x @ Wb^T + bias   [8192 x 1536], K=512   (grid 12x64, CH=12)
    gemm2p<0, 12><<<dim3(QKVW / 128, NTOK / 128), 256, 0, stream>>>(
        xb, DIM, Wb, DIM, DIM, QKV, QKVW, bc, nullptr);

    // Vt[d][j] from QKV's V block
    transpose_v<<<dim3(NTOK / 64, DIM / 64), 256, 0, stream>>>(QKV, Vt);

    // S = Q @ K^T  [8192 x 8192], K=512 ; rowss += per-row sumsq  (grid 64x64, CH=16)
    gemm2p<1, 16><<<dim3(NTOK / 128, NTOK / 128), 256, 0, stream>>>(
        QKV, QKVW, QKV + DIM, QKVW, DIM, S, NTOK, nullptr, rss);

    // O partials = S @ Vt^T, split-K=2  [8192 x 512]  (grid 4x64x2, CH=4)
    gemm2p<2, 4><<<dim3(DIM / 128, NTOK / 128, 2), 256, 0, stream>>>(
        S, NTOK, Vt, NTOK, NTOK / 2, part, DIM, nullptr, nullptr);

    // out = (p0+p1) * rsqrt(rowss)
    reduce_scale<<<NTOK * DIM / 4 / 256, 256, 0, stream>>>(part, rss, out);
}

// Round 7
// 236.527 us; speedup vs baseline: 1.6301x; 1.5656x over previous
//
#include <hip/hip_runtime.h>
#include <hip/hip_bf16.h>
#include <stdint.h>

#define NTOK 8192
#define DIM  512
#define QKVW 1536

typedef __attribute__((ext_vector_type(8))) short bf16x8;
typedef __attribute__((ext_vector_type(4))) float f32x4;

static __device__ __forceinline__ unsigned short f2b(float f) {
    union { float f; unsigned int u; } v; v.f = f;
    unsigned int r = v.u + 0x7fffu + ((v.u >> 16) & 1u);
    return (unsigned short)(r >> 16);
}

static __device__ __forceinline__ void gld_lds16(const void* g, void* l) {
    __builtin_amdgcn_global_load_lds(
        (__attribute__((address_space(1))) void*)(uintptr_t)g,
        (__attribute__((address_space(3))) void*)(uintptr_t)l,
        16, 0, 0);
}

#define SBAR() do { __builtin_amdgcn_sched_barrier(0); __builtin_amdgcn_s_barrier(); __builtin_amdgcn_sched_barrier(0); } while (0)
#define VMW0() do { __builtin_amdgcn_sched_barrier(0); asm volatile("s_waitcnt vmcnt(0)" ::: "memory"); __builtin_amdgcn_sched_barrier(0); } while (0)

// ---------------- converts ----------------

__global__ void f2b_kernel(const float* __restrict__ src, unsigned short* __restrict__ dst, int n4) {
    int i = blockIdx.x * blockDim.x + threadIdx.x;
    if (i < n4) {
        float4 f = ((const float4*)src)[i];
        ushort4 o;
        o.x = f2b(f.x); o.y = f2b(f.y); o.z = f2b(f.z); o.w = f2b(f.w);
        ((ushort4*)dst)[i] = o;
    }
}

__global__ void bias_concat(const float* __restrict__ bq, const float* __restrict__ bk,
                            const float* __restrict__ bv, float* __restrict__ bc) {
    int i = blockIdx.x * blockDim.x + threadIdx.x;
    if (i < 512)       bc[i] = bq[i];
    else if (i < 1024) bc[i] = bk[i - 512];
    else if (i < 1536) bc[i] = bv[i - 1024];
}

// ---------------- V transpose ----------------
__global__ void transpose_v(const unsigned short* __restrict__ qkv, unsigned short* __restrict__ vt) {
    __shared__ unsigned short t[64][65];
    int j0 = blockIdx.x * 64;
    int d0 = blockIdx.y * 64;
    int tid = threadIdx.x;
    int c  = tid & 63;
    int r4 = tid >> 6;
    #pragma unroll
    for (int r = r4; r < 64; r += 4)
        t[r][c] = qkv[(size_t)(j0 + r) * QKVW + 1024 + d0 + c];
    __syncthreads();
    #pragma unroll
    for (int r = r4; r < 64; r += 4)
        vt[(size_t)(d0 + r) * NTOK + j0 + c] = t[c][r];
}

// ---------------- 128x128 double-buffered GEMM, C = A * B^T ----------------
// Staging chunk c = w*128 + {l, 64+l}: LDS byte c*16 (linear dest), row = c>>2,
// slot s = c&3, global source quarter p = s ^ g(row), g(row) = (row>>1)&3.
//   -> per row the 4 slots cover all 4 quarters (full 64B line, 16 lines/instr);
//   -> LDS slot (row,s) holds quarter s^g(row).
// Frag read: quarter Q of row R at byte R*64 + (Q ^ ((R>>1)&3))*16; octet
// slot8 pattern {0,4,1,5,2,6,3,7} = bijection -> conflict-free ds_read_b128.
// Double buffer: STAGE(t+1) issued before compute(t); one vmcnt(0)+s_barrier
// per K-tile. launch_bounds(256,4) -> 4 blocks/CU. XCD-chunked swizzle.
// EPI 0: bf16 store + bias[col]            (QKV projection)
// EPI 1: bf16 store + atomic row sum-sq    (S = Q K^T)
// EPI 2: fp32 partial store (split-K by z) (O = S V)
template <int EPI, int CH>
__global__ __launch_bounds__(256, 4) void gemmx(
    const unsigned short* __restrict__ A, int lda,
    const unsigned short* __restrict__ B, int ldb,
    int Ksplit,
    void* __restrict__ Cout, int ldc,
    const float* __restrict__ bias,
    float* __restrict__ rowss) {

    __shared__ __align__(16) char lds[32768];

    const int t = threadIdx.x;
    const int l = t & 63, w = t >> 6;
    const int wr = w >> 1, wc = w & 1;

    // XCD-chunked swizzle (gridDim.y % 8 == 0, gridDim.x % CH == 0)
    const int gx = gridDim.x;
    const int nbm = gridDim.y >> 3;
    const int bid = blockIdx.y * gx + blockIdx.x;
    const int xcd = bid & 7, qq = bid >> 3;
    const int win = nbm * CH;
    const int grp = qq / win, rr = qq % win;
    const int bm = xcd * nbm + rr / CH;
    const int bn = grp * CH + rr % CH;

    const int kt0 = blockIdx.z * Ksplit;
    const int NT = Ksplit >> 5;

    // coalesced staging pointers, source quarter = (c&3) ^ ((c>>3)&3)
    const int c0 = w * 128 + l;
    const int c1 = c0 + 64;
    const int r0 = c0 >> 2, r1 = c1 >> 2;
    const int col0 = (((c0 & 3) ^ ((c0 >> 3) & 3)) << 3);
    const int col1 = (((c1 & 3) ^ ((c1 >> 3) & 3)) << 3);
    const unsigned short* gA0 = A + (size_t)(bm * 128 + r0) * lda + kt0 + col0;
    const unsigned short* gA1 = A + (size_t)(bm * 128 + r1) * lda + kt0 + col1;
    const unsigned short* gB0 = B + (size_t)(bn * 128 + r0) * ldb + kt0 + col0;
    const unsigned short* gB1 = B + (size_t)(bn * 128 + r1) * ldb + kt0 + col1;

    auto STAGE = [&](int buf, int tt) {
        char* d = lds + buf * 16384 + w * 2048;
        const int o = tt * 32;
        gld_lds16(gA0 + o, d);
        gld_lds16(gA1 + o, d + 1024);
        gld_lds16(gB0 + o, d + 8192);
        gld_lds16(gB1 + o, d + 8192 + 1024);
    };

    f32x4 acc[4][4] = {};

    // frag-read byte offsets: slot = Q ^ ((lr>>1)&3)
    const int lr = l & 15, Q = l >> 4;
    const int sw = ((Q ^ ((lr >> 1) & 3)) << 4);
    const int lrA = (wr * 64 + lr) * 64 + sw;
    const int lrB = 8192 + (wc * 64 + lr) * 64 + sw;

    STAGE(0, 0);
    VMW0();
    SBAR();

    int cur = 0;
    for (int tt = 0; tt < NT; ++tt) {
        const bool more = (tt + 1 < NT);
        if (more) STAGE(cur ^ 1, tt + 1);   // issue next-tile loads FIRST
        __builtin_amdgcn_sched_barrier(0);

        const char* lb = lds + cur * 16384;
        bf16x8 af[4], bf[4];
        #pragma unroll
        for (int m = 0; m < 4; ++m) af[m] = *(const bf16x8*)(lb + lrA + m * 1024);
        #pragma unroll
        for (int n = 0; n < 4; ++n) bf[n] = *(const bf16x8*)(lb + lrB + n * 1024);

        #pragma unroll
        for (int m = 0; m < 4; ++m)
            #pragma unroll
            for (int n = 0; n < 4; ++n)
                acc[m][n] = __builtin_amdgcn_mfma_f32_16x16x32_bf16(af[m], bf[n], acc[m][n], 0, 0, 0);

        if (more) {
            VMW0();        // next buffer landed
            SBAR();        // all waves done reading cur
            cur ^= 1;
        }
    }

    const int rbase = bm * 128 + wr * 64;
    const int cbase = bn * 128 + wc * 64;
    const int g4 = Q * 4;
    const int lc = lr;

    if constexpr (EPI == 0) {
        unsigned short* C = (unsigned short*)Cout;
        #pragma unroll
        for (int m = 0; m < 4; ++m)
            #pragma unroll
            for (int n = 0; n < 4; ++n)
                #pragma unroll
                for (int j = 0; j < 4; ++j) {
                    int rrow = rbase + m * 16 + g4 + j;
                    int ccol = cbase + n * 16 + lc;
                    C[(size_t)rrow * ldc + ccol] = f2b(acc[m][n][j] + bias[ccol]);
                }
    } else if constexpr (EPI == 1) {
        unsigned short* C = (unsigned short*)Cout;
        #pragma unroll
        for (int m = 0; m < 4; ++m)
            #pragma unroll
            for (int n = 0; n < 4; ++n)
                #pragma unroll
                for (int j = 0; j < 4; ++j) {
                    int rrow = rbase + m * 16 + g4 + j;
                    int ccol = cbase + n * 16 + lc;
                    C[(size_t)rrow * ldc + ccol] = f2b(acc[m][n][j]);
                }
        #pragma unroll
        for (int m = 0; m < 4; ++m)
            #pragma unroll
            for (int j = 0; j < 4; ++j) {
                float p = 0.f;
                #pragma unroll
                for (int n = 0; n < 4; ++n) {
                    float v = acc[m][n][j];
                    p += v * v;
                }
                p += __shfl_xor(p, 1);
                p += __shfl_xor(p, 2);
                p += __shfl_xor(p, 4);
                p += __shfl_xor(p, 8);
                if ((l & 15) == 0)
                    atomicAdd(&rowss[rbase + m * 16 + g4 + j], p);
            }
    } else {
        float* C = (float*)Cout + (size_t)blockIdx.z * NTOK * ldc;
        #pragma unroll
        for (int m = 0; m < 4; ++m)
            #pragma unroll
            for (int n = 0; n < 4; ++n)
                #pragma unroll
                for (int j = 0; j < 4; ++j) {
                    int rrow = rbase + m * 16 + g4 + j;
                    int ccol = cbase + n * 16 + lc;
                    C[(size_t)rrow * ldc + ccol] = acc[m][n][j];
                }
    }
}

// ---------------- split-K reduce + row-norm scale ----------------
__global__ void reduce_scale(const float* __restrict__ p, const float* __restrict__ rss,
                             float* __restrict__ out) {
    int i = blockIdx.x * blockDim.x + threadIdx.x;  // over NTOK*DIM/4
    const size_t stride = (size_t)NTOK * DIM / 4;
    const float4 a = ((const float4*)p)[i];
    const float4 b = ((const float4*)p)[i + stride];
    int r = i >> 7;  // (i*4)/DIM
    float s = 1.0f / fmaxf(sqrtf(rss[r]), 1e-12f);
    float4 o;
    o.x = (a.x + b.x) * s;
    o.y = (a.y + b.y) * s;
    o.z = (a.z + b.z) * s;
    o.w = (a.w + b.w) * s;
    ((float4*)out)[i] = o;
}

extern "C" void kernel_launch(void* const* d_in, const int* in_sizes, int n_in,
                              void* d_out, int out_size, void* d_ws, size_t ws_size,
                              hipStream_t stream) {
    const float* x  = (const float*)d_in[0];
    const float* Wq = (const float*)d_in[1];
    const float* bq = (const float*)d_in[2];
    const float* Wk = (const float*)d_in[3];
    const float* bk = (const float*)d_in[4];
    const float* Wv = (const float*)d_in[5];
    const float* bv = (const float*)d_in[6];
    float* out = (float*)d_out;

    char* ws = (char*)d_ws;
    size_t off = 0;
    auto alloc = [&](size_t bytes) -> void* {
        void* p = ws + off;
        off = (off + bytes + 255) & ~(size_t)255;
        return p;
    };

    unsigned short* xb   = (unsigned short*)alloc((size_t)NTOK * DIM * 2);
    unsigned short* Wb   = (unsigned short*)alloc((size_t)QKVW * DIM * 2);
    float*          bc   = (float*)alloc(QKVW * 4);
    unsigned short* QKV  = (unsigned short*)alloc((size_t)NTOK * QKVW * 2);
    unsigned short* Vt   = (unsigned short*)alloc((size_t)DIM * NTOK * 2);
    float*          rss  = (float*)alloc(NTOK * 4);
    float*          part = (float*)alloc((size_t)2 * NTOK * DIM * 4);
    unsigned short* S    = (unsigned short*)alloc((size_t)NTOK * NTOK * 2);

    // converts
    f2b_kernel<<<(NTOK * DIM / 4 + 255) / 256, 256, 0, stream>>>(x, xb, NTOK * DIM / 4);
    f2b_kernel<<<(DIM * DIM / 4 + 255) / 256, 256, 0, stream>>>(Wq, Wb, DIM * DIM / 4);
    f2b_kernel<<<(DIM * DIM / 4 + 255) / 256, 256, 0, stream>>>(Wk, Wb + DIM * DIM, DIM * DIM / 4);
    f2b_kernel<<<(DIM * DIM / 4 + 255) / 256, 256, 0, stream>>>(Wv, Wb + 2 * DIM * DIM, DIM * DIM / 4);
    bias_concat<<<6, 256, 0, stream>>>(bq, bk, bv, bc);
    hipMemsetAsync(rss, 0, NTOK * 4, stream);

    // QKV = x @ Wb^T + bias   [8192 x 1536], K=512   (grid 12x64, CH=12)
    gemmx<0, 12><<<dim3(QKVW / 128, NTOK / 128), 256, 0, stream>>>(
        xb, DIM, Wb, DIM, DIM, QKV, QKVW, bc, nullptr);

    // Vt[d][j] from QKV's V block
    transpose_v<<<dim3(NTOK / 64, DIM / 64), 256, 0, stream>>>(QKV, Vt);

    // S = Q @ K^T  [8192 x 8192], K=512 ; rowss += per-row sumsq  (grid 64x64, CH=16)
    gemmx<1, 16><<<dim3(NTOK / 128, NTOK / 128), 256, 0, stream>>>(
        QKV, QKVW, QKV + DIM, QKVW, DIM, S, NTOK, nullptr, rss);

    // O partials = S @ Vt^T, split-K=2  [8192 x 512]  (grid 4x64x2, CH=4)
    gemmx<2, 4><<<dim3(DIM / 128, NTOK / 128, 2), 256, 0, stream>>>(
        S, NTOK, Vt, NTOK, NTOK / 2, part, DIM, nullptr, nullptr);

    // out = (p0+p1) * rsqrt(rowss)
    reduce_scale<<<NTOK * DIM / 4 / 256, 256, 0, stream>>>(part, rss, out);
}